// Round 1
// baseline (174.909 us; speedup 1.0000x reference)
//
#include <hip/hip_runtime.h>

static constexpr int kNE = 50000;
static constexpr int kNR = 1000;
static constexpr int kE  = 800000;
static constexpr int kEH = 256;
static constexpr int kRH = 64;
static constexpr float kNeg = 0.01f;

static constexpr int kSegsPerB = 64;                       // 6-bit local seg
static constexpr int kSegs = 2 * kNE;                      // head segs then tail segs
static constexpr int kB = (kSegs + kSegsPerB - 1) / kSegsPerB;   // 1563 buckets
static constexpr int kCap = 1536;                          // per-bucket capacity (mean 1024)
static constexpr int kEdgesPerBin = 4096;                  // records per bin block = 8192
static constexpr int kBinBlocks  = (kE + kEdgesPerBin - 1) / kEdgesPerBin;  // 196
static constexpr int kNodeBlocks = kNE / 8;                // 6250 (512 thr = 8 waves)
static constexpr int kRelBlocks  = kNR / 8;                // 125
static constexpr int kCntPad = 2048;                       // padded counter array (>= kB)

__device__ __forceinline__ float lrelu(float x){ return x > 0.f ? x : kNeg * x; }

// ---------- K2: grid-sectioned: [bin+LDS-sort+coalesced write | node scores | rel scores] ----------
// 4096 edges (8192 records) per bin block: halves global reservation atomics, doubles
// records write-run length. LDS = cnt(8K)+cur(8K)+srt(32K) = 48 KB -> 3 blocks/CU.
__global__ __launch_bounds__(512) void k_bin_scores(
        const float* __restrict__ xe, const float* __restrict__ ahw,
        const float* __restrict__ atw, const float* __restrict__ xr,
        const float* __restrict__ arw,
        const int* __restrict__ head, const int* __restrict__ tail,
        const int* __restrict__ rel,
        float* __restrict__ s_h, float* __restrict__ s_t, float* __restrict__ s_r,
        int* __restrict__ bucket_fill, unsigned short* __restrict__ records){
    __shared__ int cnt[kCntPad];                     // 8 KB
    __shared__ int cur[kCntPad];                     // 8 KB
    __shared__ unsigned int srt[2 * kEdgesPerBin];   // 32 KB
    __shared__ int wsum[8];

    int blk = blockIdx.x;
    int tid = threadIdx.x;
    int lane = tid & 63;

    if (blk >= kBinBlocks){
        int sb = blk - kBinBlocks;
        if (sb < kNodeBlocks){
            int node = sb * 8 + (tid >> 6);
            const float4* row = (const float4*)(xe + (size_t)node * kEH);
            float4 xv = row[lane];
            float4 av = ((const float4*)ahw)[lane];
            float4 bv = ((const float4*)atw)[lane];
            float ph = xv.x*av.x + xv.y*av.y + xv.z*av.z + xv.w*av.w;
            float pt = xv.x*bv.x + xv.y*bv.y + xv.z*bv.z + xv.w*bv.w;
            #pragma unroll
            for (int o = 32; o > 0; o >>= 1){
                ph += __shfl_down(ph, o, 64);
                pt += __shfl_down(pt, o, 64);
            }
            if (lane == 0){ s_h[node] = ph; s_t[node] = pt; }
        } else {
            int r = (sb - kNodeBlocks) * 8 + (tid >> 6);
            float p = xr[(size_t)r * kRH + lane] * arw[lane];
            #pragma unroll
            for (int o = 32; o > 0; o >>= 1) p += __shfl_down(p, o, 64);
            if (lane == 0) s_r[r] = p;
        }
        return;
    }

    // ---- bin section ----
    int e0 = blk * kEdgesPerBin;
    for (int i = tid; i < kCntPad; i += 512) cnt[i] = 0;
    __syncthreads();

    // rc32 = (seg<<10)|rel ; bucket = rc32>>16 ; payload low16 = (seglocal<<10)|rel
    unsigned int recs[16];
    #pragma unroll
    for (int p = 0; p < 8; ++p){
        int e = e0 + p * 512 + tid;
        unsigned int rh = 0xFFFFFFFFu, rt = 0xFFFFFFFFu;
        if (e < kE){
            int h = head[e], t = tail[e], r = rel[e];
            rh = ((unsigned int)h << 10) | (unsigned int)r;
            rt = ((unsigned int)(kNE + t) << 10) | (unsigned int)r;
            atomicAdd(&cnt[rh >> 16], 1);
            atomicAdd(&cnt[rt >> 16], 1);
        }
        recs[p] = rh; recs[8 + p] = rt;
    }
    __syncthreads();

    // exclusive scan over cnt[2048]: thread t owns 4t..4t+3; wave shuffle-scan + wave prefix
    int c0 = cnt[4 * tid], c1 = cnt[4 * tid + 1], c2 = cnt[4 * tid + 2], c3 = cnt[4 * tid + 3];
    int v = c0 + c1 + c2 + c3;
    int x = v;
    #pragma unroll
    for (int o = 1; o < 64; o <<= 1){
        int y = __shfl_up(x, o, 64);
        if (lane >= o) x += y;
    }
    int wv = tid >> 6;
    if (lane == 63) wsum[wv] = x;
    __syncthreads();
    int wpre = 0, tot = 0;
    #pragma unroll
    for (int w = 0; w < 8; ++w){
        int s = wsum[w];
        if (w < wv) wpre += s;
        tot += s;
    }
    int base = wpre + x - v;
    cur[4 * tid]     = base;
    cur[4 * tid + 1] = base + c0;
    cur[4 * tid + 2] = base + c0 + c1;
    cur[4 * tid + 3] = base + c0 + c1 + c2;
    __syncthreads();

    // scatter into bucket-sorted LDS order
    #pragma unroll
    for (int p = 0; p < 16; ++p){
        unsigned int rc = recs[p];
        if (rc != 0xFFFFFFFFu){
            int slot = atomicAdd(&cur[rc >> 16], 1);
            srt[slot] = rc;
        }
    }
    __syncthreads();

    // reserve global runs; cur[bk] := gbase - start[bk]  (start = cur - cnt)
    for (int i = tid; i < kB; i += 512){
        int c = cnt[i];
        if (c > 0){
            int gb = atomicAdd(&bucket_fill[i], c);
            cur[i] = gb - (cur[i] - c);
        }
    }
    __syncthreads();

    // coalesced write-out of sorted runs (2-byte payloads)
    for (int j = tid; j < tot; j += 512){
        unsigned int rc = srt[j];
        int bk = rc >> 16;
        int g  = cur[bk] + j;
        if (g < kCap) records[(size_t)bk * kCap + g] = (unsigned short)(rc & 0xFFFFu);
    }
}

// ---------- K3: per-bucket LDS seg-sort (logits inline) + WAVE-per-segment softmax/aggregate ----------
// One full wave owns each segment -> degree is wave-uniform, zero intra-wave divergence
// (old 16-lane-group scheme paid max(deg) over 4 co-resident Poisson(16) groups, ~40% waste).
// max/exp phases: 64-lane record-parallel (deg~16 -> 1 trip). aggregate: 4 record-slots x
// 16 feature-quads -> 4x256B coalesced xr row gathers per trip, 2-step shfl_xor finish.
__global__ __launch_bounds__(256) void k_sort_aggregate(
        const int* __restrict__ bucket_fill, const unsigned short* __restrict__ records,
        const float* __restrict__ s_h, const float* __restrict__ s_t,
        const float* __restrict__ s_r, const float* __restrict__ xr,
        float* __restrict__ out){
    __shared__ float srl[kNR];                 // 4 KB
    __shared__ float sn[kSegsPerB];
    __shared__ unsigned short relbuf[kCap];    // 3 KB
    __shared__ float alphabuf[kCap];           // 6 KB (logits -> exp, in place)
    __shared__ int cnt[kSegsPerB], start[kSegsPerB], cur[kSegsPerB];

    int b = blockIdx.x;
    int tid = threadIdx.x;

    for (int i = tid; i < kNR; i += 256) srl[i] = s_r[i];
    if (tid < kSegsPerB){
        cnt[tid] = 0;
        int gseg = b * kSegsPerB + tid;
        float s = 0.f;
        if (gseg < kNE) s = s_h[gseg];
        else if (gseg < kSegs) s = s_t[gseg - kNE];
        sn[tid] = s;
    }
    __syncthreads();

    int nrec = bucket_fill[b];
    if (nrec > kCap) nrec = kCap;
    const unsigned short* rb = records + (size_t)b * kCap;

    unsigned short recs[6];
    #pragma unroll
    for (int p = 0; p < 6; ++p){
        int idx = p * 256 + tid;
        unsigned short rc = 0xFFFFu;
        if (idx < nrec){
            rc = rb[idx];
            atomicAdd(&cnt[rc >> 10], 1);
        }
        recs[p] = rc;
    }
    __syncthreads();
    // single-wave shuffle scan over 64 counters
    if (tid < kSegsPerB){
        int c = cnt[tid];
        int x = c;
        #pragma unroll
        for (int o = 1; o < 64; o <<= 1){
            int y = __shfl_up(x, o, 64);
            if (tid >= o) x += y;
        }
        int s = x - c;
        start[tid] = s;
        cur[tid] = s;
    }
    __syncthreads();
    // scatter rel ids into seg-grouped LDS order, computing logits inline (parallel)
    #pragma unroll
    for (int p = 0; p < 6; ++p){
        unsigned short rc = recs[p];
        if (rc != 0xFFFFu){
            int ls = rc >> 10;
            int rr = rc & 1023;
            int slot = atomicAdd(&cur[ls], 1);
            relbuf[slot] = (unsigned short)rr;
            alphabuf[slot] = lrelu(sn[ls] + srl[rr]);
        }
    }
    __syncthreads();

    // wave-per-segment: wave wv owns segments wv*16 .. wv*16+15 (all state wave-private)
    int wv   = tid >> 6;       // 0..3
    int lane = tid & 63;
    int slot = lane >> 4;      // 0..3 record slot
    int fq   = lane & 15;      // feature quad

    for (int i = 0; i < 16; ++i){
        int ls = wv * 16 + i;
        int gseg = b * kSegsPerB + ls;
        if (gseg >= kSegs) break;            // wave-uniform
        int deg = cnt[ls], st = start[ls];

        // 64-lane record-parallel max (deg ~16 -> single trip)
        float part = (lane < deg) ? alphabuf[st + lane] : -INFINITY;
        for (int k = lane + 64; k < deg; k += 64) part = fmaxf(part, alphabuf[st + k]);
        #pragma unroll
        for (int o = 1; o < 64; o <<= 1) part = fmaxf(part, __shfl_xor(part, o, 64));
        float m = part;

        // 64-lane record-parallel exp (stored back) + sum
        float ss = 0.f;
        for (int k = lane; k < deg; k += 64){
            float e = __expf(alphabuf[st + k] - m);
            alphabuf[st + k] = e;
            ss += e;
        }
        #pragma unroll
        for (int o = 1; o < 64; o <<= 1) ss += __shfl_xor(ss, o, 64);
        float inv = 1.f / (ss + 1e-16f);

        // aggregate: record-slot s reads xr row of record st+k+s, fq lanes cover 64 floats
        float4 acc = {0.f, 0.f, 0.f, 0.f};
        for (int k = slot; k < deg; k += 4){
            int rr = relbuf[st + k];
            float a = alphabuf[st + k] * inv;
            float4 v = ((const float4*)(xr + (size_t)rr * kRH))[fq];
            acc.x += a*v.x; acc.y += a*v.y; acc.z += a*v.z; acc.w += a*v.w;
        }
        // cross-slot reduce (lanes differing in bits 4,5)
        acc.x += __shfl_xor(acc.x, 16, 64); acc.y += __shfl_xor(acc.y, 16, 64);
        acc.z += __shfl_xor(acc.z, 16, 64); acc.w += __shfl_xor(acc.w, 16, 64);
        acc.x += __shfl_xor(acc.x, 32, 64); acc.y += __shfl_xor(acc.y, 32, 64);
        acc.z += __shfl_xor(acc.z, 32, 64); acc.w += __shfl_xor(acc.w, 32, 64);

        if (slot == 0){
            bool isHead = gseg < kNE;
            int node = isHead ? gseg : gseg - kNE;
            float4* op = (float4*)(out + (size_t)node * (2 * kRH) + (isHead ? 0 : kRH));
            op[fq] = acc;
        }
    }
}

extern "C" void kernel_launch(void* const* d_in, const int* in_sizes, int n_in,
                              void* d_out, int out_size, void* d_ws, size_t ws_size,
                              hipStream_t stream) {
    const float* xe  = (const float*)d_in[0];    // [50000,256] f32
    const float* xr  = (const float*)d_in[1];    // [1000,64]   f32
    const int* edge_index = (const int*)d_in[2]; // [2,800000]
    const int* rel        = (const int*)d_in[3]; // [800000]
    const float* ahw = (const float*)d_in[6];    // [256]
    const float* atw = (const float*)d_in[7];    // [256]
    const float* arw = (const float*)d_in[8];    // [64]
    float* out = (float*)d_out;                  // [50000,128] f32

    const int* head = edge_index;
    const int* tail = edge_index + kE;

    char* ws = (char*)d_ws;
    float* s_h  = (float*)ws;                    ws += kNE * sizeof(float);
    float* s_t  = (float*)ws;                    ws += kNE * sizeof(float);
    float* s_r  = (float*)ws;                    ws += kNR * sizeof(float);
    int*   bucket_fill = (int*)ws;               ws += ((kB + 255) & ~255) * sizeof(int);
    unsigned short* records = (unsigned short*)ws; ws += (size_t)kB * kCap * sizeof(unsigned short);

    hipMemsetAsync(bucket_fill, 0, kB * sizeof(int), stream);
    k_bin_scores<<<kBinBlocks + kNodeBlocks + kRelBlocks, 512, 0, stream>>>(
        xe, ahw, atw, xr, arw, head, tail, rel, s_h, s_t, s_r, bucket_fill, records);
    k_sort_aggregate<<<kB, 256, 0, stream>>>(bucket_fill, records, s_h, s_t, s_r, xr, out);
}

// Round 2
// 155.898 us; speedup vs baseline: 1.1219x; 1.1219x over previous
//
#include <hip/hip_runtime.h>

static constexpr int kNE = 50000;
static constexpr int kNR = 1000;
static constexpr int kE  = 800000;
static constexpr int kEH = 256;
static constexpr int kRH = 64;
static constexpr float kNeg = 0.01f;

static constexpr int kSegsPerB = 64;                       // 6-bit local seg
static constexpr int kSegs = 2 * kNE;                      // head segs then tail segs
static constexpr int kB = (kSegs + kSegsPerB - 1) / kSegsPerB;   // 1563 buckets
static constexpr int kCap = 1536;                          // per-bucket capacity (mean 1024)
static constexpr int kEdgesPerBin = 4096;                  // records per bin block = 8192
static constexpr int kBinBlocks  = (kE + kEdgesPerBin - 1) / kEdgesPerBin;  // 196
static constexpr int kNodeBlocks = kNE / 8;                // 6250 (512 thr = 8 waves)
static constexpr int kRelBlocks  = kNR / 8;                // 125
static constexpr int kCntPad = 2048;                       // padded counter array (>= kB)

__device__ __forceinline__ float lrelu(float x){ return x > 0.f ? x : kNeg * x; }

// ---------- K2: grid-sectioned: [bin+LDS-sort+coalesced write | node scores | rel scores] ----------
// Round-2: counting atomicAdd's return value IS the within-(block,bucket) rank, so the
// scatter needs no second atomic pass: slot = start[bucket] + rank.
__global__ __launch_bounds__(512) void k_bin_scores(
        const float* __restrict__ xe, const float* __restrict__ ahw,
        const float* __restrict__ atw, const float* __restrict__ xr,
        const float* __restrict__ arw,
        const int* __restrict__ head, const int* __restrict__ tail,
        const int* __restrict__ rel,
        float* __restrict__ s_h, float* __restrict__ s_t, float* __restrict__ s_r,
        int* __restrict__ bucket_fill, unsigned short* __restrict__ records){
    __shared__ int cnt[kCntPad];                     // 8 KB
    __shared__ int cur[kCntPad];                     // 8 KB (exclusive-scan starts; later gbase-start)
    __shared__ unsigned int srt[2 * kEdgesPerBin];   // 32 KB
    __shared__ int wsum[8];

    int blk = blockIdx.x;
    int tid = threadIdx.x;
    int lane = tid & 63;

    if (blk >= kBinBlocks){
        int sb = blk - kBinBlocks;
        if (sb < kNodeBlocks){
            int node = sb * 8 + (tid >> 6);
            const float4* row = (const float4*)(xe + (size_t)node * kEH);
            float4 xv = row[lane];
            float4 av = ((const float4*)ahw)[lane];
            float4 bv = ((const float4*)atw)[lane];
            float ph = xv.x*av.x + xv.y*av.y + xv.z*av.z + xv.w*av.w;
            float pt = xv.x*bv.x + xv.y*bv.y + xv.z*bv.z + xv.w*bv.w;
            #pragma unroll
            for (int o = 32; o > 0; o >>= 1){
                ph += __shfl_down(ph, o, 64);
                pt += __shfl_down(pt, o, 64);
            }
            if (lane == 0){ s_h[node] = ph; s_t[node] = pt; }
        } else {
            int r = (sb - kNodeBlocks) * 8 + (tid >> 6);
            float p = xr[(size_t)r * kRH + lane] * arw[lane];
            #pragma unroll
            for (int o = 32; o > 0; o >>= 1) p += __shfl_down(p, o, 64);
            if (lane == 0) s_r[r] = p;
        }
        return;
    }

    // ---- bin section ----
    int e0 = blk * kEdgesPerBin;
    for (int i = tid; i < kCntPad; i += 512) cnt[i] = 0;
    __syncthreads();

    // rc32 = (seg<<10)|rel ; bucket = rc32>>16 ; payload low16 = (seglocal<<10)|rel
    unsigned int recs[16];
    unsigned short rnk[16];
    #pragma unroll
    for (int p = 0; p < 8; ++p){
        int e = e0 + p * 512 + tid;
        unsigned int rh = 0xFFFFFFFFu, rt = 0xFFFFFFFFu;
        unsigned short kh = 0, kt = 0;
        if (e < kE){
            int h = head[e], t = tail[e], r = rel[e];
            rh = ((unsigned int)h << 10) | (unsigned int)r;
            rt = ((unsigned int)(kNE + t) << 10) | (unsigned int)r;
            kh = (unsigned short)atomicAdd(&cnt[rh >> 16], 1);
            kt = (unsigned short)atomicAdd(&cnt[rt >> 16], 1);
        }
        recs[p] = rh; recs[8 + p] = rt;
        rnk[p]  = kh; rnk[8 + p]  = kt;
    }
    __syncthreads();

    // exclusive scan over cnt[2048]: thread t owns 4t..4t+3; wave shuffle-scan + wave prefix
    int c0 = cnt[4 * tid], c1 = cnt[4 * tid + 1], c2 = cnt[4 * tid + 2], c3 = cnt[4 * tid + 3];
    int v = c0 + c1 + c2 + c3;
    int x = v;
    #pragma unroll
    for (int o = 1; o < 64; o <<= 1){
        int y = __shfl_up(x, o, 64);
        if (lane >= o) x += y;
    }
    int wv = tid >> 6;
    if (lane == 63) wsum[wv] = x;
    __syncthreads();
    int wpre = 0, tot = 0;
    #pragma unroll
    for (int w = 0; w < 8; ++w){
        int s = wsum[w];
        if (w < wv) wpre += s;
        tot += s;
    }
    int base = wpre + x - v;
    cur[4 * tid]     = base;
    cur[4 * tid + 1] = base + c0;
    cur[4 * tid + 2] = base + c0 + c1;
    cur[4 * tid + 3] = base + c0 + c1 + c2;
    __syncthreads();

    // scatter into bucket-sorted LDS order (no atomics: slot = start + rank)
    #pragma unroll
    for (int p = 0; p < 16; ++p){
        unsigned int rc = recs[p];
        if (rc != 0xFFFFFFFFu){
            int slot = cur[rc >> 16] + (int)rnk[p];
            srt[slot] = rc;
        }
    }
    __syncthreads();

    // reserve global runs; cur[bk] := gbase - start[bk] (cur still holds start)
    for (int i = tid; i < kB; i += 512){
        int c = cnt[i];
        if (c > 0){
            int gb = atomicAdd(&bucket_fill[i], c);
            cur[i] = gb - cur[i];
        }
    }
    __syncthreads();

    // coalesced write-out of sorted runs (2-byte payloads)
    for (int j = tid; j < tot; j += 512){
        unsigned int rc = srt[j];
        int bk = rc >> 16;
        int g  = cur[bk] + j;
        if (g < kCap) records[(size_t)bk * kCap + g] = (unsigned short)(rc & 0xFFFFu);
    }
}

// ---------- K3: per-bucket LDS seg-sort (logits inline) + group-parallel softmax + float4 aggregate ----------
// Round-2: back to 16-lane groups (round-1 wave-per-segment serialized 6-step reductions, -20%).
// Adds: (a) rank-from-atomic scatter (kills the contended cur[] atomic phase),
//       (b) degree-balanced group assignment via 64-key bitonic sort in wave 0 -- co-resident
//           groups get near-equal degrees, removing E[max4 Poisson]/mean ~ 25% exec-mask waste,
//       (c) softmax end-scaling (acc *= inv once instead of per-record).
__global__ __launch_bounds__(256) void k_sort_aggregate(
        const int* __restrict__ bucket_fill, const unsigned short* __restrict__ records,
        const float* __restrict__ s_h, const float* __restrict__ s_t,
        const float* __restrict__ s_r, const float* __restrict__ xr,
        float* __restrict__ out){
    __shared__ float srl[kNR];                 // 4 KB
    __shared__ float sn[kSegsPerB];
    __shared__ unsigned short relbuf[kCap];    // 3 KB
    __shared__ float alphabuf[kCap];           // 6 KB (logits -> exp, in place)
    __shared__ int cnt[kSegsPerB], start[kSegsPerB];
    __shared__ unsigned short order[kSegsPerB];

    int b = blockIdx.x;
    int tid = threadIdx.x;

    for (int i = tid; i < kNR; i += 256) srl[i] = s_r[i];
    if (tid < kSegsPerB){
        cnt[tid] = 0;
        int gseg = b * kSegsPerB + tid;
        float s = 0.f;
        if (gseg < kNE) s = s_h[gseg];
        else if (gseg < kSegs) s = s_t[gseg - kNE];
        sn[tid] = s;
    }
    __syncthreads();

    int nrec = bucket_fill[b];
    if (nrec > kCap) nrec = kCap;
    const unsigned short* rb = records + (size_t)b * kCap;

    unsigned short recs[6], rnk[6];
    #pragma unroll
    for (int p = 0; p < 6; ++p){
        int idx = p * 256 + tid;
        unsigned short rc = 0xFFFFu, rk = 0;
        if (idx < nrec){
            rc = rb[idx];
            rk = (unsigned short)atomicAdd(&cnt[rc >> 10], 1);
        }
        recs[p] = rc; rnk[p] = rk;
    }
    __syncthreads();
    // wave 0: shuffle exclusive-scan over 64 counters + bitonic degree-sort for balance
    if (tid < kSegsPerB){
        int c = cnt[tid];
        int x = c;
        #pragma unroll
        for (int o = 1; o < 64; o <<= 1){
            int y = __shfl_up(x, o, 64);
            if (tid >= o) x += y;
        }
        start[tid] = x - c;

        // bitonic ascending sort of (deg<<6 | seg) across 64 lanes
        unsigned int key = ((unsigned int)c << 6) | (unsigned int)tid;
        #pragma unroll
        for (int k = 2; k <= 64; k <<= 1){
            #pragma unroll
            for (int j = k >> 1; j > 0; j >>= 1){
                unsigned int o2 = __shfl_xor(key, j, 64);
                bool keepMin = (((tid & j) == 0) == ((tid & k) == 0));
                unsigned int mn = key < o2 ? key : o2;
                unsigned int mx = key < o2 ? o2 : key;
                key = keepMin ? mn : mx;
            }
        }
        order[tid] = (unsigned short)(key & 63u);
    }
    __syncthreads();
    // scatter rel ids into seg-grouped LDS order, logits inline (no atomics: start + rank)
    #pragma unroll
    for (int p = 0; p < 6; ++p){
        unsigned short rc = recs[p];
        if (rc != 0xFFFFu){
            int ls = rc >> 10;
            int rr = rc & 1023;
            int slot = start[ls] + (int)rnk[p];
            relbuf[slot] = (unsigned short)rr;
            alphabuf[slot] = lrelu(sn[ls] + srl[rr]);
        }
    }
    __syncthreads();

    // fused softmax + aggregate: 16-lane group per segment (intra-wave, no barriers).
    // iteration i gives the 16 groups segments of adjacent degree-rank -> balanced exec masks.
    int grp = tid >> 4;        // 0..15
    int sub = tid & 15;        // feature quad / softmax stride
    #pragma unroll
    for (int i = 0; i < 4; ++i){
        int ls = order[i * 16 + grp];
        int gseg = b * kSegsPerB + ls;
        if (gseg >= kSegs) continue;
        int deg = cnt[ls], st = start[ls];

        // group-parallel max
        float part = -INFINITY;
        for (int k = sub; k < deg; k += 16) part = fmaxf(part, alphabuf[st + k]);
        #pragma unroll
        for (int o = 1; o < 16; o <<= 1) part = fmaxf(part, __shfl_xor(part, o, 64));
        float m = part;

        // group-parallel exp (stored back) + sum
        float ss = 0.f;
        for (int k = sub; k < deg; k += 16){
            float e = __expf(alphabuf[st + k] - m);
            alphabuf[st + k] = e;
            ss += e;
        }
        #pragma unroll
        for (int o = 1; o < 16; o <<= 1) ss += __shfl_xor(ss, o, 64);
        float inv = 1.f / (ss + 1e-16f);

        // aggregate with raw exp weights; scale by inv once at the end
        float4 acc = {0.f, 0.f, 0.f, 0.f};
        int k = 0;
        for (; k + 4 <= deg; k += 4){
            int r0 = relbuf[st + k],     r1 = relbuf[st + k + 1];
            int r2 = relbuf[st + k + 2], r3 = relbuf[st + k + 3];
            float a0 = alphabuf[st + k],     a1 = alphabuf[st + k + 1];
            float a2 = alphabuf[st + k + 2], a3 = alphabuf[st + k + 3];
            float4 v0 = ((const float4*)(xr + (size_t)r0 * kRH))[sub];
            float4 v1 = ((const float4*)(xr + (size_t)r1 * kRH))[sub];
            float4 v2 = ((const float4*)(xr + (size_t)r2 * kRH))[sub];
            float4 v3 = ((const float4*)(xr + (size_t)r3 * kRH))[sub];
            acc.x += a0*v0.x + a1*v1.x + a2*v2.x + a3*v3.x;
            acc.y += a0*v0.y + a1*v1.y + a2*v2.y + a3*v3.y;
            acc.z += a0*v0.z + a1*v1.z + a2*v2.z + a3*v3.z;
            acc.w += a0*v0.w + a1*v1.w + a2*v2.w + a3*v3.w;
        }
        for (; k < deg; ++k){
            int rr = relbuf[st + k];
            float a = alphabuf[st + k];
            float4 v = ((const float4*)(xr + (size_t)rr * kRH))[sub];
            acc.x += a*v.x; acc.y += a*v.y; acc.z += a*v.z; acc.w += a*v.w;
        }
        acc.x *= inv; acc.y *= inv; acc.z *= inv; acc.w *= inv;

        bool isHead = gseg < kNE;
        int node = isHead ? gseg : gseg - kNE;
        float4* op = (float4*)(out + (size_t)node * (2 * kRH) + (isHead ? 0 : kRH));
        op[sub] = acc;
    }
}

extern "C" void kernel_launch(void* const* d_in, const int* in_sizes, int n_in,
                              void* d_out, int out_size, void* d_ws, size_t ws_size,
                              hipStream_t stream) {
    const float* xe  = (const float*)d_in[0];    // [50000,256] f32
    const float* xr  = (const float*)d_in[1];    // [1000,64]   f32
    const int* edge_index = (const int*)d_in[2]; // [2,800000]
    const int* rel        = (const int*)d_in[3]; // [800000]
    const float* ahw = (const float*)d_in[6];    // [256]
    const float* atw = (const float*)d_in[7];    // [256]
    const float* arw = (const float*)d_in[8];    // [64]
    float* out = (float*)d_out;                  // [50000,128] f32

    const int* head = edge_index;
    const int* tail = edge_index + kE;

    char* ws = (char*)d_ws;
    float* s_h  = (float*)ws;                    ws += kNE * sizeof(float);
    float* s_t  = (float*)ws;                    ws += kNE * sizeof(float);
    float* s_r  = (float*)ws;                    ws += kNR * sizeof(float);
    int*   bucket_fill = (int*)ws;               ws += ((kB + 255) & ~255) * sizeof(int);
    unsigned short* records = (unsigned short*)ws; ws += (size_t)kB * kCap * sizeof(unsigned short);

    hipMemsetAsync(bucket_fill, 0, kB * sizeof(int), stream);
    k_bin_scores<<<kBinBlocks + kNodeBlocks + kRelBlocks, 512, 0, stream>>>(
        xe, ahw, atw, xr, arw, head, tail, rel, s_h, s_t, s_r, bucket_fill, records);
    k_sort_aggregate<<<kB, 256, 0, stream>>>(bucket_fill, records, s_h, s_t, s_r, xr, out);
}

// Round 3
// 148.983 us; speedup vs baseline: 1.1740x; 1.0464x over previous
//
#include <hip/hip_runtime.h>

static constexpr int kNE = 50000;
static constexpr int kNR = 1000;
static constexpr int kE  = 800000;
static constexpr int kEH = 256;
static constexpr int kRH = 64;
static constexpr float kNeg = 0.01f;

static constexpr int kSegsPerB = 64;                       // 6-bit local seg
static constexpr int kSegs = 2 * kNE;                      // head segs then tail segs
static constexpr int kB = (kSegs + kSegsPerB - 1) / kSegsPerB;   // 1563 buckets
static constexpr int kCap = 1536;                          // per-bucket records (mean 1024, mu+16sigma)
static constexpr int kEdgesPerBin = 2048;                  // records per bin block = 4096
static constexpr int kChunkRecs  = 2 * kEdgesPerBin;       // 4096
static constexpr int kBinBlocks  = (kE + kEdgesPerBin - 1) / kEdgesPerBin;  // 391
static constexpr int kTabCols    = 392;                    // padded chunk columns
static constexpr int kNodeBlocks = kNE / 8;                // 6250 (512 thr = 8 waves)
static constexpr int kRelBlocks  = kNR / 8;                // 125
static constexpr int kCntPad = 2048;                       // padded counter array (>= kB)

__device__ __forceinline__ float lrelu(float x){ return x > 0.f ? x : kNeg * x; }

// ---------- K2: grid-sectioned: [bin+LDS-sort+deterministic dump | node scores | rel scores] ----------
// Round-3: NO global atomics. Each bin block dumps its bucket-sorted records to a private
// contiguous chunk (pair-packed dword stores) + writes its column of the transposed
// per-bucket start table. The 196-deep same-address atomic chains on bucket_fill (the
// suspected ~25 us serialization) are gone. 2048-edge bins double parallelism (391 blocks).
__global__ __launch_bounds__(512) void k_bin_scores(
        const float* __restrict__ xe, const float* __restrict__ ahw,
        const float* __restrict__ atw, const float* __restrict__ xr,
        const float* __restrict__ arw,
        const int* __restrict__ head, const int* __restrict__ tail,
        const int* __restrict__ rel,
        float* __restrict__ s_h, float* __restrict__ s_t, float* __restrict__ s_r,
        unsigned short* __restrict__ chunk, unsigned short* __restrict__ tab){
    __shared__ int cnt[kCntPad];                 // 8 KB
    __shared__ int cur[kCntPad];                 // 8 KB (exclusive-scan starts)
    __shared__ unsigned int srt[kChunkRecs];     // 16 KB
    __shared__ int wsum[8];

    int blk = blockIdx.x;
    int tid = threadIdx.x;
    int lane = tid & 63;

    if (blk >= kBinBlocks){
        int sb = blk - kBinBlocks;
        if (sb < kNodeBlocks){
            int node = sb * 8 + (tid >> 6);
            const float4* row = (const float4*)(xe + (size_t)node * kEH);
            float4 xv = row[lane];
            float4 av = ((const float4*)ahw)[lane];
            float4 bv = ((const float4*)atw)[lane];
            float ph = xv.x*av.x + xv.y*av.y + xv.z*av.z + xv.w*av.w;
            float pt = xv.x*bv.x + xv.y*bv.y + xv.z*bv.z + xv.w*bv.w;
            #pragma unroll
            for (int o = 32; o > 0; o >>= 1){
                ph += __shfl_down(ph, o, 64);
                pt += __shfl_down(pt, o, 64);
            }
            if (lane == 0){ s_h[node] = ph; s_t[node] = pt; }
        } else {
            int r = (sb - kNodeBlocks) * 8 + (tid >> 6);
            float p = xr[(size_t)r * kRH + lane] * arw[lane];
            #pragma unroll
            for (int o = 32; o > 0; o >>= 1) p += __shfl_down(p, o, 64);
            if (lane == 0) s_r[r] = p;
        }
        return;
    }

    // ---- bin section: 2048 edges -> 4096 records ----
    int e0 = blk * kEdgesPerBin;
    for (int i = tid; i < kCntPad; i += 512) cnt[i] = 0;
    __syncthreads();

    // rc32 = (seg<<10)|rel ; bucket = rc32>>16 ; payload low16 = (seglocal<<10)|rel
    unsigned int recs[8];
    unsigned short rnk[8];
    #pragma unroll
    for (int p = 0; p < 4; ++p){
        int e = e0 + p * 512 + tid;
        unsigned int rh = 0xFFFFFFFFu, rt = 0xFFFFFFFFu;
        unsigned short kh = 0, kt = 0;
        if (e < kE){
            int h = head[e], t = tail[e], r = rel[e];
            rh = ((unsigned int)h << 10) | (unsigned int)r;
            rt = ((unsigned int)(kNE + t) << 10) | (unsigned int)r;
            kh = (unsigned short)atomicAdd(&cnt[rh >> 16], 1);
            kt = (unsigned short)atomicAdd(&cnt[rt >> 16], 1);
        }
        recs[p] = rh; recs[4 + p] = rt;
        rnk[p]  = kh; rnk[4 + p]  = kt;
    }
    __syncthreads();

    // exclusive scan over cnt[2048]: thread t owns 4t..4t+3; wave shuffle-scan + wave prefix
    int c0 = cnt[4 * tid], c1 = cnt[4 * tid + 1], c2 = cnt[4 * tid + 2], c3 = cnt[4 * tid + 3];
    int v = c0 + c1 + c2 + c3;
    int x = v;
    #pragma unroll
    for (int o = 1; o < 64; o <<= 1){
        int y = __shfl_up(x, o, 64);
        if (lane >= o) x += y;
    }
    int wv = tid >> 6;
    if (lane == 63) wsum[wv] = x;
    __syncthreads();
    int wpre = 0, tot = 0;
    #pragma unroll
    for (int w = 0; w < 8; ++w){
        int s = wsum[w];
        if (w < wv) wpre += s;
        tot += s;
    }
    int base = wpre + x - v;
    cur[4 * tid]     = base;
    cur[4 * tid + 1] = base + c0;
    cur[4 * tid + 2] = base + c0 + c1;
    cur[4 * tid + 3] = base + c0 + c1 + c2;
    __syncthreads();

    // scatter into bucket-sorted LDS order (no atomics: slot = start + rank)
    #pragma unroll
    for (int p = 0; p < 8; ++p){
        unsigned int rc = recs[p];
        if (rc != 0xFFFFFFFFu){
            int slot = cur[rc >> 16] + (int)rnk[p];
            srt[slot] = rc;
        }
    }
    __syncthreads();

    // coalesced pair-packed dump of sorted payloads (tot is always even: h/t pairs)
    unsigned int* cw = (unsigned int*)(chunk + (size_t)blk * kChunkRecs);
    for (int j2 = tid; j2 < (tot >> 1); j2 += 512){
        unsigned int lo = srt[2 * j2] & 0xFFFFu;
        unsigned int hi = srt[2 * j2 + 1] & 0xFFFFu;
        cw[j2] = lo | (hi << 16);
    }
    // transposed start table: column blk of every bucket row (+ total row)
    for (int i = tid; i < kB; i += 512)
        tab[(size_t)i * kTabCols + blk] = (unsigned short)cur[i];
    if (tid == 0)
        tab[(size_t)kB * kTabCols + blk] = (unsigned short)tot;
}

// ---------- K3: gather per-chunk runs -> LDS compact -> seg-sort -> group softmax/aggregate ----------
// Round-3: records arrive as 391 bucket-contiguous runs (mean ~2.6 recs); per-thread run copy
// with block prefix-scan compacts them into LDS. Max pass folded into scatter via ordered-uint
// atomicMax. Rest identical to round-2 (16-lane groups + bitonic degree balance, verified).
__global__ __launch_bounds__(256) void k_sort_aggregate(
        const unsigned short* __restrict__ chunk, const unsigned short* __restrict__ tab,
        const float* __restrict__ s_h, const float* __restrict__ s_t,
        const float* __restrict__ s_r, const float* __restrict__ xr,
        float* __restrict__ out){
    __shared__ float srl[kNR];                 // 4 KB
    __shared__ float sn[kSegsPerB];
    __shared__ unsigned short arr[kCap];       // 3 KB compacted records
    __shared__ unsigned short relbuf[kCap];    // 3 KB
    __shared__ float alphabuf[kCap];           // 6 KB (logits -> exp, in place)
    __shared__ int cnt[kSegsPerB], start[kSegsPerB];
    __shared__ unsigned int mx[kSegsPerB];
    __shared__ unsigned short order[kSegsPerB];
    __shared__ int gsum[4];

    int b = blockIdx.x;
    int tid = threadIdx.x;
    int lane = tid & 63;
    int wv = tid >> 6;

    for (int i = tid; i < kNR; i += 256) srl[i] = s_r[i];
    if (tid < kSegsPerB){
        cnt[tid] = 0;
        mx[tid] = 0u;
        int gseg = b * kSegsPerB + tid;
        float s = 0.f;
        if (gseg < kNE) s = s_h[gseg];
        else if (gseg < kSegs) s = s_t[gseg - kNE];
        sn[tid] = s;
    }
    __syncthreads();

    // ---- gather: copy this bucket's run from each chunk, compacted into arr ----
    const unsigned short* rowS = tab + (size_t)b * kTabCols;
    const unsigned short* rowE = tab + (size_t)(b + 1) * kTabCols;
    int nrec = 0;
    for (int c0 = 0; c0 < kBinBlocks; c0 += 256){
        int c = c0 + tid;
        int s = 0, L = 0;
        if (c < kBinBlocks){
            s = rowS[c];
            L = (int)rowE[c] - s;
        }
        int x = L;
        #pragma unroll
        for (int o = 1; o < 64; o <<= 1){
            int y = __shfl_up(x, o, 64);
            if (lane >= o) x += y;
        }
        if (lane == 63) gsum[wv] = x;
        __syncthreads();
        int wpre = 0, stot = 0;
        #pragma unroll
        for (int w = 0; w < 4; ++w){
            int g = gsum[w];
            if (w < wv) wpre += g;
            stot += g;
        }
        int off = nrec + wpre + x - L;
        if (off + L > kCap) L = max(0, kCap - off);
        const unsigned short* src = chunk + (size_t)c * kChunkRecs + s;
        for (int i = 0; i < L; ++i) arr[off + i] = src[i];
        nrec += stot;
        __syncthreads();
    }
    if (nrec > kCap) nrec = kCap;

    // ---- count (rank-from-atomic) ----
    unsigned short recs[6], rnk[6];
    #pragma unroll
    for (int p = 0; p < 6; ++p){
        int idx = p * 256 + tid;
        unsigned short rc = 0xFFFFu, rk = 0;
        if (idx < nrec){
            rc = arr[idx];
            rk = (unsigned short)atomicAdd(&cnt[rc >> 10], 1);
        }
        recs[p] = rc; rnk[p] = rk;
    }
    __syncthreads();
    // wave 0: shuffle exclusive-scan over 64 counters + bitonic degree-sort for balance
    if (tid < kSegsPerB){
        int c = cnt[tid];
        int x = c;
        #pragma unroll
        for (int o = 1; o < 64; o <<= 1){
            int y = __shfl_up(x, o, 64);
            if (tid >= o) x += y;
        }
        start[tid] = x - c;

        unsigned int key = ((unsigned int)c << 6) | (unsigned int)tid;
        #pragma unroll
        for (int k = 2; k <= 64; k <<= 1){
            #pragma unroll
            for (int j = k >> 1; j > 0; j >>= 1){
                unsigned int o2 = __shfl_xor(key, j, 64);
                bool keepMin = (((tid & j) == 0) == ((tid & k) == 0));
                unsigned int mn = key < o2 ? key : o2;
                unsigned int mxk = key < o2 ? o2 : key;
                key = keepMin ? mn : mxk;
            }
        }
        order[tid] = (unsigned short)(key & 63u);
    }
    __syncthreads();
    // scatter into seg-grouped order; logits inline; seg-max via ordered-uint atomicMax
    #pragma unroll
    for (int p = 0; p < 6; ++p){
        unsigned short rc = recs[p];
        if (rc != 0xFFFFu){
            int ls = rc >> 10;
            int rr = rc & 1023;
            int slot = start[ls] + (int)rnk[p];
            float lg = lrelu(sn[ls] + srl[rr]);
            unsigned int s32 = __float_as_uint(lg);
            unsigned int key = (s32 & 0x80000000u) ? ~s32 : (s32 | 0x80000000u);
            atomicMax(&mx[ls], key);
            relbuf[slot] = (unsigned short)rr;
            alphabuf[slot] = lg;
        }
    }
    __syncthreads();

    // fused softmax + aggregate: 16-lane group per segment (intra-wave, no barriers).
    // iteration i gives the 16 groups segments of adjacent degree-rank -> balanced exec masks.
    int grp = tid >> 4;        // 0..15
    int sub = tid & 15;        // feature quad / softmax stride
    #pragma unroll
    for (int i = 0; i < 4; ++i){
        int ls = order[i * 16 + grp];
        int gseg = b * kSegsPerB + ls;
        if (gseg >= kSegs) continue;
        int deg = cnt[ls], st = start[ls];

        unsigned int u = mx[ls];
        float m = __uint_as_float((u & 0x80000000u) ? (u & 0x7FFFFFFFu) : ~u);

        // group-parallel exp (stored back) + sum
        float ss = 0.f;
        for (int k = sub; k < deg; k += 16){
            float e = __expf(alphabuf[st + k] - m);
            alphabuf[st + k] = e;
            ss += e;
        }
        #pragma unroll
        for (int o = 1; o < 16; o <<= 1) ss += __shfl_xor(ss, o, 64);
        float inv = 1.f / (ss + 1e-16f);

        // aggregate with raw exp weights; scale by inv once at the end
        float4 acc = {0.f, 0.f, 0.f, 0.f};
        int k = 0;
        for (; k + 4 <= deg; k += 4){
            int r0 = relbuf[st + k],     r1 = relbuf[st + k + 1];
            int r2 = relbuf[st + k + 2], r3 = relbuf[st + k + 3];
            float a0 = alphabuf[st + k],     a1 = alphabuf[st + k + 1];
            float a2 = alphabuf[st + k + 2], a3 = alphabuf[st + k + 3];
            float4 v0 = ((const float4*)(xr + (size_t)r0 * kRH))[sub];
            float4 v1 = ((const float4*)(xr + (size_t)r1 * kRH))[sub];
            float4 v2 = ((const float4*)(xr + (size_t)r2 * kRH))[sub];
            float4 v3 = ((const float4*)(xr + (size_t)r3 * kRH))[sub];
            acc.x += a0*v0.x + a1*v1.x + a2*v2.x + a3*v3.x;
            acc.y += a0*v0.y + a1*v1.y + a2*v2.y + a3*v3.y;
            acc.z += a0*v0.z + a1*v1.z + a2*v2.z + a3*v3.z;
            acc.w += a0*v0.w + a1*v1.w + a2*v2.w + a3*v3.w;
        }
        for (; k < deg; ++k){
            int rr = relbuf[st + k];
            float a = alphabuf[st + k];
            float4 v = ((const float4*)(xr + (size_t)rr * kRH))[sub];
            acc.x += a*v.x; acc.y += a*v.y; acc.z += a*v.z; acc.w += a*v.w;
        }
        acc.x *= inv; acc.y *= inv; acc.z *= inv; acc.w *= inv;

        bool isHead = gseg < kNE;
        int node = isHead ? gseg : gseg - kNE;
        float4* op = (float4*)(out + (size_t)node * (2 * kRH) + (isHead ? 0 : kRH));
        op[sub] = acc;
    }
}

extern "C" void kernel_launch(void* const* d_in, const int* in_sizes, int n_in,
                              void* d_out, int out_size, void* d_ws, size_t ws_size,
                              hipStream_t stream) {
    const float* xe  = (const float*)d_in[0];    // [50000,256] f32
    const float* xr  = (const float*)d_in[1];    // [1000,64]   f32
    const int* edge_index = (const int*)d_in[2]; // [2,800000]
    const int* rel        = (const int*)d_in[3]; // [800000]
    const float* ahw = (const float*)d_in[6];    // [256]
    const float* atw = (const float*)d_in[7];    // [256]
    const float* arw = (const float*)d_in[8];    // [64]
    float* out = (float*)d_out;                  // [50000,128] f32

    const int* head = edge_index;
    const int* tail = edge_index + kE;

    char* ws = (char*)d_ws;
    float* s_h  = (float*)ws;                    ws += kNE * sizeof(float);
    float* s_t  = (float*)ws;                    ws += kNE * sizeof(float);
    float* s_r  = (float*)ws;                    ws += ((kNR + 256) & ~255) * sizeof(float);
    unsigned short* chunk = (unsigned short*)ws; ws += (size_t)kBinBlocks * kChunkRecs * sizeof(unsigned short);
    unsigned short* tab   = (unsigned short*)ws; ws += (size_t)(kB + 1) * kTabCols * sizeof(unsigned short);

    k_bin_scores<<<kBinBlocks + kNodeBlocks + kRelBlocks, 512, 0, stream>>>(
        xe, ahw, atw, xr, arw, head, tail, rel, s_h, s_t, s_r, chunk, tab);
    k_sort_aggregate<<<kB, 256, 0, stream>>>(chunk, tab, s_h, s_t, s_r, xr, out);
}

// Round 4
// 145.492 us; speedup vs baseline: 1.2022x; 1.0240x over previous
//
#include <hip/hip_runtime.h>

static constexpr int kNE = 50000;
static constexpr int kNR = 1000;
static constexpr int kE  = 800000;
static constexpr int kEH = 256;
static constexpr int kRH = 64;
static constexpr float kNeg = 0.01f;

static constexpr int kSegsPerB = 64;                       // 6-bit local seg
static constexpr int kSegs = 2 * kNE;                      // head segs then tail segs
static constexpr int kB = (kSegs + kSegsPerB - 1) / kSegsPerB;   // 1563 buckets
static constexpr int kCap = 1536;                          // per-bucket records (mean 1024, mu+16sigma)
static constexpr int kEdgesPerBin = 2048;                  // records per bin block = 4096
static constexpr int kChunkRecs  = 2 * kEdgesPerBin;       // 4096
static constexpr int kBinBlocks  = (kE + kEdgesPerBin - 1) / kEdgesPerBin;  // 391
static constexpr int kTabW       = kB + 1;                 // row: starts[0..kB-1], tot at [kB]
static constexpr int kNodeBlocks = kNE / 8;                // 6250 (512 thr = 8 waves)
static constexpr int kRelBlocks  = kNR / 8;                // 125
static constexpr int kCntPad = 2048;                       // padded counter array (>= kB)

__device__ __forceinline__ float lrelu(float x){ return x > 0.f ? x : kNeg * x; }

// ---------- K2: grid-sectioned: [bin+LDS-sort+deterministic dump | node scores | rel scores] ----------
// Round-4: ROW-MAJOR start table tab[blk][bucket] -- one contiguous 3.1 KB coalesced store
// per block (round-3 wrote a 784B-strided column: 1563 partial-cacheline RMWs/block, ~39 MB
// of write-allocate traffic for a 1.2 MB table).
__global__ __launch_bounds__(512) void k_bin_scores(
        const float* __restrict__ xe, const float* __restrict__ ahw,
        const float* __restrict__ atw, const float* __restrict__ xr,
        const float* __restrict__ arw,
        const int* __restrict__ head, const int* __restrict__ tail,
        const int* __restrict__ rel,
        float* __restrict__ s_h, float* __restrict__ s_t, float* __restrict__ s_r,
        unsigned short* __restrict__ chunk, unsigned short* __restrict__ tab){
    __shared__ int cnt[kCntPad];                 // 8 KB
    __shared__ int cur[kCntPad];                 // 8 KB (exclusive-scan starts)
    __shared__ unsigned int srt[kChunkRecs];     // 16 KB
    __shared__ int wsum[8];

    int blk = blockIdx.x;
    int tid = threadIdx.x;
    int lane = tid & 63;

    if (blk >= kBinBlocks){
        int sb = blk - kBinBlocks;
        if (sb < kNodeBlocks){
            int node = sb * 8 + (tid >> 6);
            const float4* row = (const float4*)(xe + (size_t)node * kEH);
            float4 xv = row[lane];
            float4 av = ((const float4*)ahw)[lane];
            float4 bv = ((const float4*)atw)[lane];
            float ph = xv.x*av.x + xv.y*av.y + xv.z*av.z + xv.w*av.w;
            float pt = xv.x*bv.x + xv.y*bv.y + xv.z*bv.z + xv.w*bv.w;
            #pragma unroll
            for (int o = 32; o > 0; o >>= 1){
                ph += __shfl_down(ph, o, 64);
                pt += __shfl_down(pt, o, 64);
            }
            if (lane == 0){ s_h[node] = ph; s_t[node] = pt; }
        } else {
            int r = (sb - kNodeBlocks) * 8 + (tid >> 6);
            float p = xr[(size_t)r * kRH + lane] * arw[lane];
            #pragma unroll
            for (int o = 32; o > 0; o >>= 1) p += __shfl_down(p, o, 64);
            if (lane == 0) s_r[r] = p;
        }
        return;
    }

    // ---- bin section: 2048 edges -> 4096 records ----
    int e0 = blk * kEdgesPerBin;
    for (int i = tid; i < kCntPad; i += 512) cnt[i] = 0;
    __syncthreads();

    // rc32 = (seg<<10)|rel ; bucket = rc32>>16 ; payload low16 = (seglocal<<10)|rel
    unsigned int recs[8];
    unsigned short rnk[8];
    #pragma unroll
    for (int p = 0; p < 4; ++p){
        int e = e0 + p * 512 + tid;
        unsigned int rh = 0xFFFFFFFFu, rt = 0xFFFFFFFFu;
        unsigned short kh = 0, kt = 0;
        if (e < kE){
            int h = head[e], t = tail[e], r = rel[e];
            rh = ((unsigned int)h << 10) | (unsigned int)r;
            rt = ((unsigned int)(kNE + t) << 10) | (unsigned int)r;
            kh = (unsigned short)atomicAdd(&cnt[rh >> 16], 1);
            kt = (unsigned short)atomicAdd(&cnt[rt >> 16], 1);
        }
        recs[p] = rh; recs[4 + p] = rt;
        rnk[p]  = kh; rnk[4 + p]  = kt;
    }
    __syncthreads();

    // exclusive scan over cnt[2048]: thread t owns 4t..4t+3; wave shuffle-scan + wave prefix
    int c0 = cnt[4 * tid], c1 = cnt[4 * tid + 1], c2 = cnt[4 * tid + 2], c3 = cnt[4 * tid + 3];
    int v = c0 + c1 + c2 + c3;
    int x = v;
    #pragma unroll
    for (int o = 1; o < 64; o <<= 1){
        int y = __shfl_up(x, o, 64);
        if (lane >= o) x += y;
    }
    int wv = tid >> 6;
    if (lane == 63) wsum[wv] = x;
    __syncthreads();
    int wpre = 0, tot = 0;
    #pragma unroll
    for (int w = 0; w < 8; ++w){
        int s = wsum[w];
        if (w < wv) wpre += s;
        tot += s;
    }
    int base = wpre + x - v;
    cur[4 * tid]     = base;
    cur[4 * tid + 1] = base + c0;
    cur[4 * tid + 2] = base + c0 + c1;
    cur[4 * tid + 3] = base + c0 + c1 + c2;
    __syncthreads();

    // scatter into bucket-sorted LDS order (no atomics: slot = start + rank)
    #pragma unroll
    for (int p = 0; p < 8; ++p){
        unsigned int rc = recs[p];
        if (rc != 0xFFFFFFFFu){
            int slot = cur[rc >> 16] + (int)rnk[p];
            srt[slot] = rc;
        }
    }
    __syncthreads();

    // coalesced pair-packed dump of sorted payloads (tot is always even: h/t pairs)
    unsigned int* cw = (unsigned int*)(chunk + (size_t)blk * kChunkRecs);
    for (int j2 = tid; j2 < (tot >> 1); j2 += 512){
        unsigned int lo = srt[2 * j2] & 0xFFFFu;
        unsigned int hi = srt[2 * j2 + 1] & 0xFFFFu;
        cw[j2] = lo | (hi << 16);
    }
    // row-major start table (contiguous, coalesced); [kB] holds tot
    unsigned short* trow = tab + (size_t)blk * kTabW;
    for (int i = tid; i < kB; i += 512) trow[i] = (unsigned short)cur[i];
    if (tid == 0) trow[kB] = (unsigned short)tot;
}

// ---------- K3: flat-parallel gather -> seg-sort -> group softmax/aggregate ----------
// Round-4 gather: build cumOff[c]/srcBase[c] in LDS, then record j is found by a uniform
// 9-step binary search and loaded straight into registers. Consecutive j -> consecutive
// source addresses within runs (semi-coalesced), zero exec-mask imbalance, no arr[] LDS
// round-trip (round-3 did per-thread serial run copies: ~3x waste + 64 lines/wave).
__global__ __launch_bounds__(256) void k_sort_aggregate(
        const unsigned short* __restrict__ chunk, const unsigned short* __restrict__ tab,
        const float* __restrict__ s_h, const float* __restrict__ s_t,
        const float* __restrict__ s_r, const float* __restrict__ xr,
        float* __restrict__ out){
    __shared__ float srl[kNR];                 // 4 KB
    __shared__ float sn[kSegsPerB];
    __shared__ unsigned short relbuf[kCap];    // 3 KB
    __shared__ float alphabuf[kCap];           // 6 KB (logits -> exp, in place)
    __shared__ int cumOff[kBinBlocks + 1];     // 1.57 KB
    __shared__ int srcBase[kBinBlocks];        // 1.56 KB
    __shared__ int cnt[kSegsPerB], start[kSegsPerB];
    __shared__ unsigned int mx[kSegsPerB];
    __shared__ unsigned short order[kSegsPerB];
    __shared__ int gsum[4];

    int b = blockIdx.x;
    int tid = threadIdx.x;
    int lane = tid & 63;
    int wv = tid >> 6;

    for (int i = tid; i < kNR; i += 256) srl[i] = s_r[i];
    if (tid < kSegsPerB){
        cnt[tid] = 0;
        mx[tid] = 0u;
        int gseg = b * kSegsPerB + tid;
        float s = 0.f;
        if (gseg < kNE) s = s_h[gseg];
        else if (gseg < kSegs) s = s_t[gseg - kNE];
        sn[tid] = s;
    }
    if (tid == 0) cumOff[0] = 0;
    __syncthreads();

    // ---- build run table: cumOff (inclusive prefix of run lengths) + srcBase ----
    int nrecBase = 0;
    for (int c0 = 0; c0 < kBinBlocks; c0 += 256){
        int c = c0 + tid;
        int L = 0;
        if (c < kBinBlocks){
            const unsigned short* trow = tab + (size_t)c * kTabW;
            int s = trow[b];
            L = (int)trow[b + 1] - s;        // b+1 <= kB; trow[kB] = tot covers last bucket
            srcBase[c] = c * kChunkRecs + s;
        }
        int x = L;
        #pragma unroll
        for (int o = 1; o < 64; o <<= 1){
            int y = __shfl_up(x, o, 64);
            if (lane >= o) x += y;
        }
        if (lane == 63) gsum[wv] = x;
        __syncthreads();
        int wpre = 0, stot = 0;
        #pragma unroll
        for (int w = 0; w < 4; ++w){
            int g = gsum[w];
            if (w < wv) wpre += g;
            stot += g;
        }
        if (c < kBinBlocks) cumOff[c + 1] = nrecBase + wpre + x;
        nrecBase += stot;
        __syncthreads();
    }
    int nrec = nrecBase > kCap ? kCap : nrecBase;

    // ---- fetch + count (rank-from-atomic), records straight into registers ----
    unsigned short recs[6], rnk[6];
    #pragma unroll
    for (int p = 0; p < 6; ++p){
        int j = p * 256 + tid;
        unsigned short rc = 0xFFFFu, rk = 0;
        if (j < nrec){
            int lo = 0, hi = kBinBlocks;      // invariant: cumOff[lo] <= j < cumOff[hi]
            #pragma unroll 1
            while (hi - lo > 1){
                int mid = (lo + hi) >> 1;
                if (cumOff[mid] <= j) lo = mid; else hi = mid;
            }
            rc = chunk[srcBase[lo] + (j - cumOff[lo])];
            rk = (unsigned short)atomicAdd(&cnt[rc >> 10], 1);
        }
        recs[p] = rc; rnk[p] = rk;
    }
    __syncthreads();
    // wave 0: shuffle exclusive-scan over 64 counters + bitonic degree-sort for balance
    if (tid < kSegsPerB){
        int c = cnt[tid];
        int x = c;
        #pragma unroll
        for (int o = 1; o < 64; o <<= 1){
            int y = __shfl_up(x, o, 64);
            if (tid >= o) x += y;
        }
        start[tid] = x - c;

        unsigned int key = ((unsigned int)c << 6) | (unsigned int)tid;
        #pragma unroll
        for (int k = 2; k <= 64; k <<= 1){
            #pragma unroll
            for (int j = k >> 1; j > 0; j >>= 1){
                unsigned int o2 = __shfl_xor(key, j, 64);
                bool keepMin = (((tid & j) == 0) == ((tid & k) == 0));
                unsigned int mn = key < o2 ? key : o2;
                unsigned int mxk = key < o2 ? o2 : key;
                key = keepMin ? mn : mxk;
            }
        }
        order[tid] = (unsigned short)(key & 63u);
    }
    __syncthreads();
    // scatter into seg-grouped order; logits inline; seg-max via ordered-uint atomicMax
    #pragma unroll
    for (int p = 0; p < 6; ++p){
        unsigned short rc = recs[p];
        if (rc != 0xFFFFu){
            int ls = rc >> 10;
            int rr = rc & 1023;
            int slot = start[ls] + (int)rnk[p];
            float lg = lrelu(sn[ls] + srl[rr]);
            unsigned int s32 = __float_as_uint(lg);
            unsigned int key = (s32 & 0x80000000u) ? ~s32 : (s32 | 0x80000000u);
            atomicMax(&mx[ls], key);
            relbuf[slot] = (unsigned short)rr;
            alphabuf[slot] = lg;
        }
    }
    __syncthreads();

    // fused softmax + aggregate: 16-lane group per segment (intra-wave, no barriers).
    // iteration i gives the 16 groups segments of adjacent degree-rank -> balanced exec masks.
    int grp = tid >> 4;        // 0..15
    int sub = tid & 15;        // feature quad / softmax stride
    #pragma unroll
    for (int i = 0; i < 4; ++i){
        int ls = order[i * 16 + grp];
        int gseg = b * kSegsPerB + ls;
        if (gseg >= kSegs) continue;
        int deg = cnt[ls], st = start[ls];

        unsigned int u = mx[ls];
        float m = __uint_as_float((u & 0x80000000u) ? (u & 0x7FFFFFFFu) : ~u);

        // group-parallel exp (stored back) + sum
        float ss = 0.f;
        for (int k = sub; k < deg; k += 16){
            float e = __expf(alphabuf[st + k] - m);
            alphabuf[st + k] = e;
            ss += e;
        }
        #pragma unroll
        for (int o = 1; o < 16; o <<= 1) ss += __shfl_xor(ss, o, 64);
        float inv = 1.f / (ss + 1e-16f);

        // aggregate with raw exp weights; scale by inv once at the end
        float4 acc = {0.f, 0.f, 0.f, 0.f};
        int k = 0;
        for (; k + 4 <= deg; k += 4){
            int r0 = relbuf[st + k],     r1 = relbuf[st + k + 1];
            int r2 = relbuf[st + k + 2], r3 = relbuf[st + k + 3];
            float a0 = alphabuf[st + k],     a1 = alphabuf[st + k + 1];
            float a2 = alphabuf[st + k + 2], a3 = alphabuf[st + k + 3];
            float4 v0 = ((const float4*)(xr + (size_t)r0 * kRH))[sub];
            float4 v1 = ((const float4*)(xr + (size_t)r1 * kRH))[sub];
            float4 v2 = ((const float4*)(xr + (size_t)r2 * kRH))[sub];
            float4 v3 = ((const float4*)(xr + (size_t)r3 * kRH))[sub];
            acc.x += a0*v0.x + a1*v1.x + a2*v2.x + a3*v3.x;
            acc.y += a0*v0.y + a1*v1.y + a2*v2.y + a3*v3.y;
            acc.z += a0*v0.z + a1*v1.z + a2*v2.z + a3*v3.z;
            acc.w += a0*v0.w + a1*v1.w + a2*v2.w + a3*v3.w;
        }
        for (; k < deg; ++k){
            int rr = relbuf[st + k];
            float a = alphabuf[st + k];
            float4 v = ((const float4*)(xr + (size_t)rr * kRH))[sub];
            acc.x += a*v.x; acc.y += a*v.y; acc.z += a*v.z; acc.w += a*v.w;
        }
        acc.x *= inv; acc.y *= inv; acc.z *= inv; acc.w *= inv;

        bool isHead = gseg < kNE;
        int node = isHead ? gseg : gseg - kNE;
        float4* op = (float4*)(out + (size_t)node * (2 * kRH) + (isHead ? 0 : kRH));
        op[sub] = acc;
    }
}

extern "C" void kernel_launch(void* const* d_in, const int* in_sizes, int n_in,
                              void* d_out, int out_size, void* d_ws, size_t ws_size,
                              hipStream_t stream) {
    const float* xe  = (const float*)d_in[0];    // [50000,256] f32
    const float* xr  = (const float*)d_in[1];    // [1000,64]   f32
    const int* edge_index = (const int*)d_in[2]; // [2,800000]
    const int* rel        = (const int*)d_in[3]; // [800000]
    const float* ahw = (const float*)d_in[6];    // [256]
    const float* atw = (const float*)d_in[7];    // [256]
    const float* arw = (const float*)d_in[8];    // [64]
    float* out = (float*)d_out;                  // [50000,128] f32

    const int* head = edge_index;
    const int* tail = edge_index + kE;

    char* ws = (char*)d_ws;
    float* s_h  = (float*)ws;                    ws += kNE * sizeof(float);
    float* s_t  = (float*)ws;                    ws += kNE * sizeof(float);
    float* s_r  = (float*)ws;                    ws += ((kNR + 256) & ~255) * sizeof(float);
    unsigned short* chunk = (unsigned short*)ws; ws += (size_t)kBinBlocks * kChunkRecs * sizeof(unsigned short);
    unsigned short* tab   = (unsigned short*)ws; ws += (size_t)kBinBlocks * kTabW * sizeof(unsigned short);

    k_bin_scores<<<kBinBlocks + kNodeBlocks + kRelBlocks, 512, 0, stream>>>(
        xe, ahw, atw, xr, arw, head, tail, rel, s_h, s_t, s_r, chunk, tab);
    k_sort_aggregate<<<kB, 256, 0, stream>>>(chunk, tab, s_h, s_t, s_r, xr, out);
}